// Round 9
// baseline (545.306 us; speedup 1.0000x reference)
//
#include <hip/hip_runtime.h>
#include <hip/hip_bf16.h>

// Problem constants
#define B_   2
#define N_   2048
#define D_   128
#define H_   16
#define ALL_ 2048
#define M_   (B_*N_)    // 4096 total rows
#define BH_  (B_*H_)    // 32 (batch*heads)

typedef __bf16 bf16;
typedef __bf16 bf16x8 __attribute__((ext_vector_type(8)));
typedef __bf16 bf16x4 __attribute__((ext_vector_type(4)));
typedef float  floatx4 __attribute__((ext_vector_type(4)));

#define MFMA32K(a,b,c) __builtin_amdgcn_mfma_f32_16x16x32_bf16((a),(b),(c),0,0,0)

// async global->LDS DMA, 16B per lane (m97 pattern).
__device__ inline void load_lds16(const bf16* g, bf16* l) {
    __builtin_amdgcn_global_load_lds((const __attribute__((address_space(1))) void*)g,
                                     (__attribute__((address_space(3))) void*)l, 16, 0, 0);
}

#define WAITCNT_VM(n) ((0xF << 8) | (0x7 << 4) | (n))

// ---------------------------------------------------------------------------
// Software grid barrier. VALID because all 512 blocks are co-resident by
// construction: LDS 73728 B -> exactly 2 blocks/CU, grid 512 = 256 CU x 2.
// No dispatch-order assumption: every resident block increments and spins.
// __threadfence() (agent scope) provides the cross-XCD writeback/invalidate;
// the atomics are device-scope (m20). Counters zeroed per launch by a
// stream-ordered hipMemsetAsync (graph-capturable).
// ---------------------------------------------------------------------------
__device__ inline void gbar(unsigned* cnt, unsigned target) {
    __syncthreads();
    __threadfence();                       // release: make my writes visible
    if (threadIdx.x == 0) {
        __hip_atomic_fetch_add(cnt, 1u, __ATOMIC_RELEASE, __HIP_MEMORY_SCOPE_AGENT);
        while (__hip_atomic_load(cnt, __ATOMIC_ACQUIRE, __HIP_MEMORY_SCOPE_AGENT) < target)
            __builtin_amdgcn_s_sleep(2);
    }
    __syncthreads();
    __threadfence();                       // acquire: see others' writes
}

// ---------------------------------------------------------------------------
// FUSED single-launch MHA (normal launch + software barriers). R8's
// cooperative attempt failed with absmax == max|ref| => launch silently
// no-opped (cooperative-in-graph); phase bodies were never disproven.
// Phase bodies are instruction-identical to measured-best standalone
// versions (prep/qkv: R3; flash: R7 80.1 µs pipeline; out: R3 (256,4)
// emulated as 2 two-wave sub-units with the same qt->XCD mapping).
//
// FRAGMENT-MAJOR LAYOUTS (unchanged):
//  A/B-frag canonical (16x16x32): elem j of lane (lrow=lane&15,quad=lane>>4)
//    A[m=lrow][k=kf*32+quad*8+j]  /  B[k=kf*32+quad*8+j][n=lrow]
//  Wf (Wq/Wk/Wv): [ct 128][kf 4][lane][8]; xf: [rt 256][kf 4][lane][8]
//  Qf/Kf: [bh][t 128][kf 4][lane][8]
//  Vf:  [bh][kb 32][nf 8][g 2][lane][8]  PERMUTED k
//  ctxf: [qt 256][kf 64][lane][8] PERMUTED k — written from flash O accs
//  Wof: [ct 8][kf 64][lane][8] PERMUTED k to MATCH ctxf
//  mbias pre-scaled by log2(e) (exp2 path).
// ---------------------------------------------------------------------------
__global__ __launch_bounds__(256, 2) void fused_mha(
        const float* __restrict__ x,   const int* __restrict__ mask,
        const float* __restrict__ Wq,  const float* __restrict__ bq,
        const float* __restrict__ Wk,  const float* __restrict__ bk,
        const float* __restrict__ Wv,  const float* __restrict__ bv,
        const float* __restrict__ Wo,  const float* __restrict__ bo,
        float* __restrict__ out,
        bf16* __restrict__ Wqf, bf16* __restrict__ Wkf, bf16* __restrict__ Wvf,
        bf16* __restrict__ Wof, bf16* __restrict__ xf,
        bf16* __restrict__ Qf,  bf16* __restrict__ Kf,  bf16* __restrict__ Vf,
        bf16* __restrict__ ctxf, float* __restrict__ mbias,
        unsigned* __restrict__ syncc)
{
    __shared__ __align__(16) char smem[73728];

    int bid = blockIdx.x, tid = threadIdx.x;
    int lane = tid & 63, wave = tid >> 6;
    int lrow = lane & 15, quad = lane >> 4;
    floatx4 zero4 = {0.f, 0.f, 0.f, 0.f};

    // ===================== phase P: prep (368 virtual blocks) =============
    {
        bf16* pw = (bf16*)smem;
        if (bid < 192) {
            // Wq/Wk/Wv [128][2048]: block = 64 k-rows (half) x 64 cols
            int m = bid / 64, rest = bid % 64;
            int cgp = rest >> 1, kh = rest & 1;
            const float* W = (m == 0) ? Wq : (m == 1) ? Wk : Wv;
            bf16* Wf       = (m == 0) ? Wqf : (m == 1) ? Wkf : Wvf;
            int slot = tid & 15, rowb = tid >> 4;
#pragma unroll
            for (int i = 0; i < 4; i++) {
                int rl_ = rowb + i * 16;
                float4 v = *(const float4*)(W + (size_t)(kh * 64 + rl_) * 2048 + cgp * 64 + slot * 4);
                bf16x4 o; o[0]=(bf16)v.x; o[1]=(bf16)v.y; o[2]=(bf16)v.z; o[3]=(bf16)v.w;
                *(bf16x4*)(&pw[rl_ * 68 + slot * 4]) = o;
            }
            __syncthreads();
            int ctl = wave;
#pragma unroll
            for (int kfl = 0; kfl < 2; kfl++) {
                bf16x8 w;
#pragma unroll
                for (int j = 0; j < 8; j++) w[j] = pw[(kfl * 32 + quad * 8 + j) * 68 + ctl * 16 + lrow];
                *(bf16x8*)(Wf + (size_t)((cgp * 4 + ctl) * 4 + kh * 2 + kfl) * 512 + lane * 8) = w;
            }
        } else if (bid < 224) {
            // Wo [2048][128]: 128 k-rows x 64-col half, PERMUTED pack
            int idx = bid - 192;
            int kb16 = idx >> 1, ch = idx & 1;
            int k0 = kb16 * 128;
            int slot = tid & 15, rowb = tid >> 4;
#pragma unroll
            for (int i = 0; i < 8; i++) {
                int r = rowb + i * 16;
                float4 v = *(const float4*)(Wo + (size_t)(k0 + r) * 128 + ch * 64 + slot * 4);
                bf16x4 o; o[0]=(bf16)v.x; o[1]=(bf16)v.y; o[2]=(bf16)v.z; o[3]=(bf16)v.w;
                *(bf16x4*)(&pw[r * 68 + slot * 4]) = o;
            }
            __syncthreads();
            int ctl = wave;
            int ct = ch * 4 + ctl;
#pragma unroll
            for (int kfl = 0; kfl < 4; kfl++) {
                bf16x8 w;
#pragma unroll
                for (int j = 0; j < 8; j++)
                    w[j] = pw[(kfl * 32 + ((j >> 2) << 4) + quad * 4 + (j & 3)) * 68 + ctl * 16 + lrow];
                *(bf16x8*)(Wof + (size_t)(ct * 64 + kb16 * 4 + kfl) * 512 + lane * 8) = w;
            }
        } else if (bid < 352) {
            // x [4096][128] fp32 -> xf frags, 32 rows per virtual block
            int idx = bid - 224, r0 = idx * 32;
            int slot = tid & 31, rowb = tid >> 5;
#pragma unroll
            for (int i = 0; i < 4; i++) {
                int r = rowb + i * 8;
                float4 v = *(const float4*)(x + (size_t)(r0 + r) * 128 + slot * 4);
                bf16x4 o; o[0]=(bf16)v.x; o[1]=(bf16)v.y; o[2]=(bf16)v.z; o[3]=(bf16)v.w;
                *(bf16x4*)(&pw[r * 136 + slot * 4]) = o;
            }
            __syncthreads();
            int rtl = wave >> 1;
            int kf2 = (wave & 1) * 2;
#pragma unroll
            for (int kfl = 0; kfl < 2; kfl++) {
                int kf = kf2 + kfl;
                bf16x8 w = *(const bf16x8*)(&pw[(rtl * 16 + lrow) * 136 + kf * 32 + quad * 8]);
                *(bf16x8*)(xf + (size_t)((idx * 2 + rtl) * 4 + kf) * 512 + lane * 8) = w;
            }
        } else if (bid < 368) {
            int e = (bid - 352) * 256 + tid;
            mbias[e] = mask[e] ? 0.0f : -43.2808512f;   // exp2 -> ~9e-14 ~ 0
        }
    }
    gbar(&syncc[0], 512);

    // ===================== phase A: qkv (4 chunks per block) ==============
    {
        bf16 (*tile)[72] = (bf16(*)[72])smem;
        for (int chunk = 0; chunk < 4; chunk++) {
            int vb = bid * 4 + chunk;          // x-fastest: vb&63 = row-blk
            int r0b = (vb & 63) * 64;
            int c0  = (vb >> 6) * 64;
            int cg4 = c0 >> 4;

            int rt = (r0b >> 4) + wave;
            bf16x8 a[4];
#pragma unroll
            for (int kf = 0; kf < 4; kf++)
                a[kf] = *(const bf16x8*)(xf + (size_t)(rt * 4 + kf) * 512 + lane * 8);

            int bb = r0b >> 11;
            int h  = c0 >> 7;
            int bhw = bb * 16 + h;
            int tile16 = (r0b & 2047) >> 4;
            int kbt = (r0b & 2047) >> 6;

#pragma unroll
            for (int z = 0; z < 3; z++) {
                const float* bias = (z == 0) ? bq : (z == 1) ? bk : bv;
                const bf16*  Wf   = (z == 0) ? Wqf : (z == 1) ? Wkf : Wvf;

                floatx4 acc[4] = {zero4, zero4, zero4, zero4};
#pragma unroll
                for (int kf = 0; kf < 4; kf++) {
#pragma unroll
                    for (int nf = 0; nf < 4; nf++) {
                        bf16x8 b = *(const bf16x8*)(Wf + (size_t)((cg4 + nf) * 4 + kf) * 512 + lane * 8);
                        acc[nf] = MFMA32K(a[kf], b, acc[nf]);
                    }
                }

#pragma unroll
                for (int nf = 0; nf < 4; nf++) {
                    int col = nf * 16 + lrow;
                    float bvv = bias[c0 + col];
#pragma unroll
                    for (int r = 0; r < 4; r++) {
                        int row = wave * 16 + quad * 4 + r;
                        bf16 val = (bf16)(acc[nf][r] + bvv);
                        if (z < 2) tile[row][col] = val;
                        else       tile[col][row] = val;
                    }
                }
                __syncthreads();

                if (z < 2) {
                    bf16* dst = (z == 0) ? Qf : Kf;
                    int s = wave;
                    int kfbase = (c0 & 127) >> 5;
                    size_t fbase = ((size_t)bhw * 128 + tile16 + s) * 4 + kfbase;
#pragma unroll
                    for (int kfl = 0; kfl < 2; kfl++) {
                        bf16x8 w = *(const bf16x8*)(&tile[s * 16 + lrow][kfl * 32 + quad * 8]);
                        *(bf16x8*)(dst + (fbase + kfl) * 512 + lane * 8) = w;
                    }
                } else {
                    int nfl = wave;
                    int nfbase = (c0 & 127) >> 4;
                    size_t fbase = (((size_t)bhw * 32 + kbt) * 8 + (nfbase + nfl)) * 2;
#pragma unroll
                    for (int g = 0; g < 2; g++) {
                        bf16x4 a0 = *(const bf16x4*)(&tile[nfl * 16 + lrow][g * 32 + quad * 4]);
                        bf16x4 a1 = *(const bf16x4*)(&tile[nfl * 16 + lrow][g * 32 + 16 + quad * 4]);
                        bf16x8 w;
                        w[0]=a0[0]; w[1]=a0[1]; w[2]=a0[2]; w[3]=a0[3];
                        w[4]=a1[0]; w[5]=a1[1]; w[6]=a1[2]; w[7]=a1[3];
                        *(bf16x8*)(Vf + (fbase + g) * 512 + lane * 8) = w;
                    }
                }
                if (z < 2) __syncthreads();
            }
            __syncthreads();   // protect tile before next chunk overwrites
        }
    }
    gbar(&syncc[1], 512);

    // ===================== phase F: flash (R7 pipelined body) =============
    {
        bf16* sm = (bf16*)smem;                 // 4 rotating K bufs x 16 KB
        float* mbL = (float*)(smem + 65536);    // mbias row (8 KB)

        int xcd = bid & 7, seq = bid >> 3;
        int bh  = xcd * 4 + (seq >> 4);
        int qblk = seq & 15;
        int b  = bh >> 4;
        int q0 = qblk * 128 + wave * 32;

        const float* mbp = mbias + b * N_;
        const bf16* kbase = Kf + (size_t)bh * 262144;
        const bf16* vbase = Vf + (size_t)bh * 262144 + lane * 8;

        bf16x8 qf[2][4];
#pragma unroll
        for (int u = 0; u < 2; u++)
#pragma unroll
            for (int kf = 0; kf < 4; kf++)
                qf[u][kf] = *(const bf16x8*)(Qf + (size_t)(((size_t)bh * 128 + (q0 >> 4) + u) * 4 + kf) * 512 + lane * 8);

        bf16x8 ones;
#pragma unroll
        for (int j = 0; j < 8; j++) ones[j] = (bf16)1.0f;

        floatx4 O[2][8];
#pragma unroll
        for (int u = 0; u < 2; u++)
#pragma unroll
            for (int nf = 0; nf < 8; nf++) O[u][nf] = zero4;
        floatx4 Oext[2] = {zero4, zero4};

        const float scale = 0.12751742f;        // (1/sqrt(128)) * log2(e)

        // prologue: K(0..2) -> buf0..2 + mbias; drain once
#pragma unroll
        for (int tt = 0; tt < 3; tt++) {
#pragma unroll
            for (int i = 0; i < 4; i++) {
                int seg = wave * 4 + i;
                load_lds16(kbase + (size_t)tt * 8192 + seg * 512 + lane * 8,
                           &sm[tt * 8192 + seg * 512]);
            }
        }
#pragma unroll
        for (int i = 0; i < 2; i++) {
            int seg = wave * 2 + i;
            load_lds16((const bf16*)(mbp + seg * 256) + lane * 8, (bf16*)(mbL + seg * 256));
        }
        __builtin_amdgcn_s_waitcnt(WAITCNT_VM(0));
        __builtin_amdgcn_s_barrier();

        // prologue compute: QK(0) -> pa/pb
        bf16x8 pa[2], pb[2];
#pragma unroll
        for (int s = 0; s < 4; s++) {
            floatx4 S0 = zero4, S1 = zero4;
            __builtin_amdgcn_s_setprio(1);
#pragma unroll
            for (int kf = 0; kf < 4; kf++) {
                bf16x8 kfr = *(const bf16x8*)(&sm[((s * 4 + kf) * 64 + lane) * 8]);
                S0 = MFMA32K(kfr, qf[0][kf], S0);
                S1 = MFMA32K(kfr, qf[1][kf], S1);
            }
            __builtin_amdgcn_s_setprio(0);
            float4 mb4 = *(const float4*)(mbL + s * 16 + quad * 4);
            const float* mbr = (const float*)&mb4;
            int o = (s & 1) * 4;
#pragma unroll
            for (int r = 0; r < 4; r++) {
                float p0 = __builtin_amdgcn_exp2f(fmaf(S0[r], scale, mbr[r]));
                float p1 = __builtin_amdgcn_exp2f(fmaf(S1[r], scale, mbr[r]));
                if (s < 2) { pa[0][o + r] = (bf16)p0; pa[1][o + r] = (bf16)p1; }
                else       { pb[0][o + r] = (bf16)p0; pb[1][o + r] = (bf16)p1; }
            }
        }

        for (int t = 0; t < 32; t++) {
            const bf16* vsrc = vbase + (size_t)t * 8192;
            bf16x8 vreg[16];
#pragma unroll
            for (int f = 0; f < 16; f++)
                vreg[f] = *(const bf16x8*)(vsrc + f * 512);

            if (t < 29) {
                int dst = ((t + 3) & 3) << 13;
                const bf16* ksrc = kbase + (size_t)(t + 3) * 8192;
#pragma unroll
                for (int i = 0; i < 4; i++) {
                    int seg = wave * 4 + i;
                    load_lds16(ksrc + seg * 512 + lane * 8, &sm[dst + seg * 512]);
                }
            }

            int nb = ((t + 1) & 3) << 13;
            int tn = t + 1;
            bf16x8 pan[2], pbn[2];
            floatx4 Sa0, Sa1, Sb0, Sb1;

            if (t < 31) {
                Sa0 = zero4; Sa1 = zero4; Sb0 = zero4; Sb1 = zero4;
                __builtin_amdgcn_s_setprio(1);
#pragma unroll
                for (int kf = 0; kf < 4; kf++) {
                    bf16x8 kfr = *(const bf16x8*)(&sm[nb + ((0 * 4 + kf) * 64 + lane) * 8]);
                    Sa0 = MFMA32K(kfr, qf[0][kf], Sa0);
                    Sa1 = MFMA32K(kfr, qf[1][kf], Sa1);
                }
#pragma unroll
                for (int kf = 0; kf < 4; kf++) {
                    bf16x8 kfr = *(const bf16x8*)(&sm[nb + ((1 * 4 + kf) * 64 + lane) * 8]);
                    Sb0 = MFMA32K(kfr, qf[0][kf], Sb0);
                    Sb1 = MFMA32K(kfr, qf[1][kf], Sb1);
                }
                __builtin_amdgcn_s_setprio(0);
                float4 mb4 = *(const float4*)(mbL + tn * 64 + 0 * 16 + quad * 4);
                const float* mbr = (const float*)&mb4;
#pragma unroll
                for (int r = 0; r < 4; r++) {
                    pan[0][r] = (bf16)__builtin_amdgcn_exp2f(fmaf(Sa0[r], scale, mbr[r]));
                    pan[1][r] = (bf16)__builtin_amdgcn_exp2f(fmaf(Sa1[r], scale, mbr[r]));
                }
            }

            __builtin_amdgcn_s_setprio(1);
            Oext[0] = MFMA32K(ones, pa[0], Oext[0]);
            Oext[1] = MFMA32K(ones, pa[1], Oext[1]);
#pragma unroll
            for (int nf = 0; nf < 8; nf++) {
                O[0][nf] = MFMA32K(vreg[nf * 2], pa[0], O[0][nf]);
                O[1][nf] = MFMA32K(vreg[nf * 2], pa[1], O[1][nf]);
            }
            __builtin_amdgcn_s_setprio(0);

            if (t < 31) {
                float4 mb4 = *(const float4*)(mbL + tn * 64 + 1 * 16 + quad * 4);
                const float* mbr = (const float*)&mb4;
#pragma unroll
                for (int r = 0; r < 4; r++) {
                    pan[0][4 + r] = (bf16)__builtin_amdgcn_exp2f(fmaf(Sb0[r], scale, mbr[r]));
                    pan[1][4 + r] = (bf16)__builtin_amdgcn_exp2f(fmaf(Sb1[r], scale, mbr[r]));
                }
                Sa0 = zero4; Sa1 = zero4; Sb0 = zero4; Sb1 = zero4;
                __builtin_amdgcn_s_setprio(1);
#pragma unroll
                for (int kf = 0; kf < 4; kf++) {
                    bf16x8 kfr = *(const bf16x8*)(&sm[nb + ((2 * 4 + kf) * 64 + lane) * 8]);
                    Sa0 = MFMA32K(kfr, qf[0][kf], Sa0);
                    Sa1 = MFMA32K(kfr, qf[1][kf], Sa1);
                }
#pragma unroll
                for (int kf = 0; kf < 4; kf++) {
                    bf16x8 kfr = *(const bf16x8*)(&sm[nb + ((3 * 4 + kf) * 64 + lane) * 8]);
                    Sb0 = MFMA32K(kfr, qf[0][kf], Sb0);
                    Sb1 = MFMA32K(kfr, qf[1][kf], Sb1);
                }
                __builtin_amdgcn_s_setprio(0);
                float4 mb4b = *(const float4*)(mbL + tn * 64 + 2 * 16 + quad * 4);
                const float* mbr2 = (const float*)&mb4b;
#pragma unroll
                for (int r = 0; r < 4; r++) {
                    pbn[0][r] = (bf16)__builtin_amdgcn_exp2f(fmaf(Sa0[r], scale, mbr2[r]));
                    pbn[1][r] = (bf16)__builtin_amdgcn_exp2f(fmaf(Sa1[r], scale, mbr2[r]));
                }
            }

            __builtin_amdgcn_s_setprio(1);
            Oext[0] = MFMA32K(ones, pb[0], Oext[0]);
            Oext[1] = MFMA32K(ones, pb[1], Oext[1]);
#pragma unroll
            for (int nf = 0; nf < 8; nf++) {
                O[0][nf] = MFMA32K(vreg[nf * 2 + 1], pb[0], O[0][nf]);
                O[1][nf] = MFMA32K(vreg[nf * 2 + 1], pb[1], O[1][nf]);
            }
            __builtin_amdgcn_s_setprio(0);

            if (t < 31) {
                float4 mb4 = *(const float4*)(mbL + tn * 64 + 3 * 16 + quad * 4);
                const float* mbr = (const float*)&mb4;
#pragma unroll
                for (int r = 0; r < 4; r++) {
                    pbn[0][4 + r] = (bf16)__builtin_amdgcn_exp2f(fmaf(Sb0[r], scale, mbr[r]));
                    pbn[1][4 + r] = (bf16)__builtin_amdgcn_exp2f(fmaf(Sb1[r], scale, mbr[r]));
                }
#pragma unroll
                for (int u = 0; u < 2; u++) { pa[u] = pan[u]; pb[u] = pbn[u]; }
            }

            __builtin_amdgcn_s_waitcnt(WAITCNT_VM(4));
            __builtin_amdgcn_s_barrier();
        }

        // epilogue: normalize + DIRECT permuted-concat A-frag stores
        const int* mp = mask + b * N_;
        int h4 = (bh & 15) * 4;
        size_t qtb = (size_t)b * 128 + (q0 >> 4);
#pragma unroll
        for (int u = 0; u < 2; u++) {
            float lsum = Oext[u][0];
            int q = q0 + u * 16 + lrow;
            float rl = (mp[q] && lsum > 0.f) ? (1.0f / lsum) : 0.f;
#pragma unroll
            for (int g = 0; g < 4; g++) {
                bf16x8 w;
#pragma unroll
                for (int j = 0; j < 4; j++) {
                    w[j]     = (bf16)(O[u][2 * g][j]     * rl);
                    w[j + 4] = (bf16)(O[u][2 * g + 1][j] * rl);
                }
                *(bf16x8*)(ctxf + ((qtb + u) * 64 + h4 + g) * 512 + lane * 8) = w;
            }
        }
    }
    gbar(&syncc[2], 512);

    // ===================== phase O: out_proj (2 sub-units) ================
    // Emulates R3's grid (256,4) x 128thr: sub-unit su handles virtual
    // block vb = su*512 + bid -> qt = vb&255, cty = vb>>8. A qt's four cty
    // land on bids {qt, qt+256} (same XCD mod 8) matching R3's L2 locality.
    {
        float* red = (float*)smem;             // [2 sub][512]
        int sub = wave >> 1, w2 = wave & 1;
        int vb = sub * 512 + bid;
        int qt = vb & 255, cty = vb >> 8;      // bid<256: cty 0/2; else 1/3
        int ct = cty * 2;
        int r0 = qt * 16, c0 = ct * 16;

        floatx4 acc[2] = {zero4, zero4};
        const bf16* ap = ctxf + ((size_t)qt * 64 + w2 * 32) * 512 + lane * 8;
        const bf16* b0 = Wof + ((size_t)ct * 64 + w2 * 32) * 512 + lane * 8;
        const bf16* b1 = b0 + (size_t)64 * 512;
#pragma unroll 4
        for (int kf = 0; kf < 32; kf++) {
            bf16x8 a  = *(const bf16x8*)(ap + (size_t)kf * 512);
            bf16x8 w0 = *(const bf16x8*)(b0 + (size_t)kf * 512);
            bf16x8 w1 = *(const bf16x8*)(b1 + (size_t)kf * 512);
            acc[0] = MFMA32K(a, w0, acc[0]);
            acc[1] = MFMA32K(a, w1, acc[1]);
        }
        if (w2 == 1) {
#pragma unroll
            for (int nf = 0; nf < 2; nf++)
#pragma unroll
                for (int r = 0; r < 4; r++)
                    red[sub * 512 + nf * 256 + r * 64 + lane] = acc[nf][r];
        }
        __syncthreads();
        if (w2 == 0) {
#pragma unroll
            for (int nf = 0; nf < 2; nf++) {
                int col = c0 + nf * 16 + lrow;
                float bv = bo[col];
#pragma unroll
                for (int r = 0; r < 4; r++) {
                    int m = r0 + quad * 4 + r;
                    out[(size_t)m * 128 + col] =
                        acc[nf][r] + red[sub * 512 + nf * 256 + r * 64 + lane] + bv;
                }
            }
        }
    }
}

// ---------------------------------------------------------------------------
extern "C" void kernel_launch(void* const* d_in, const int* in_sizes, int n_in,
                              void* d_out, int out_size, void* d_ws, size_t ws_size,
                              hipStream_t stream) {
    const float* x    = (const float*)d_in[0];
    const int*   mask = (const int*)d_in[1];
    const float* Wq   = (const float*)d_in[2];
    const float* bq   = (const float*)d_in[3];
    const float* Wk   = (const float*)d_in[4];
    const float* bk   = (const float*)d_in[5];
    const float* Wv   = (const float*)d_in[6];
    const float* bv   = (const float*)d_in[7];
    const float* Wo   = (const float*)d_in[8];
    const float* bo   = (const float*)d_in[9];
    float* out = (float*)d_out;

    char* ws = (char*)d_ws;
    size_t off = 0;
    bf16* Wqf = (bf16*)(ws + off); off += (size_t)262144 * 2;
    bf16* Wkf = (bf16*)(ws + off); off += (size_t)262144 * 2;
    bf16* Wvf = (bf16*)(ws + off); off += (size_t)262144 * 2;
    bf16* Wof = (bf16*)(ws + off); off += (size_t)262144 * 2;
    bf16* xf  = (bf16*)(ws + off); off += (size_t)524288 * 2;
    size_t qkv_elems = (size_t)BH_ * N_ * 128;           // 8.4M
    bf16* Qf  = (bf16*)(ws + off); off += qkv_elems * 2; // fragment-major
    bf16* Kf  = (bf16*)(ws + off); off += qkv_elems * 2;
    bf16* Vf  = (bf16*)(ws + off); off += qkv_elems * 2;
    bf16* ctxf = (bf16*)(ws + off); off += (size_t)M_ * ALL_ * 2;
    float* mbias = (float*)(ws + off); off += (size_t)B_ * N_ * 4;
    unsigned* syncc = (unsigned*)(ws + off); off += 256; // 3 barrier counters
    (void)ws_size; (void)in_sizes; (void)n_in; (void)out_size;

    hipMemsetAsync(syncc, 0, 3 * sizeof(unsigned), stream);

    fused_mha<<<512, 256, 0, stream>>>(x, mask, Wq, bq, Wk, bk, Wv, bv, Wo, bo,
                                       out, Wqf, Wkf, Wvf, Wof, xf,
                                       Qf, Kf, Vf, ctxf, mbias, syncc);
}

// Round 11
// 505.795 us; speedup vs baseline: 1.0781x; 1.0781x over previous
//
#include <hip/hip_runtime.h>
#include <hip/hip_bf16.h>

// Problem constants
#define B_   2
#define N_   2048
#define D_   128
#define H_   16
#define ALL_ 2048
#define M_   (B_*N_)    // 4096 total rows
#define BH_  (B_*H_)    // 32 (batch*heads)

typedef __bf16 bf16;
typedef __bf16 bf16x8 __attribute__((ext_vector_type(8)));
typedef __bf16 bf16x4 __attribute__((ext_vector_type(4)));
typedef float  floatx4 __attribute__((ext_vector_type(4)));

#define MFMA32K(a,b,c) __builtin_amdgcn_mfma_f32_16x16x32_bf16((a),(b),(c),0,0,0)

// async global->LDS DMA, 16B per lane (m97 pattern).
__device__ inline void load_lds16(const bf16* g, bf16* l) {
    __builtin_amdgcn_global_load_lds((const __attribute__((address_space(1))) void*)g,
                                     (__attribute__((address_space(3))) void*)l, 16, 0, 0);
}

#define WAITCNT_VM(n) ((0xF << 8) | (0x7 << 4) | (n))

// ---------------------------------------------------------------------------
// Software grid barrier, v3. R9 lesson: ACQUIRE-agent polling emits a cache
// INVALIDATE per poll -> 512 spinners = continuous L1/L2 invalidation storm
// (507 µs @ 6.5% MfmaUtil, FETCH +20MB). R10 lesson: __hip_atomic_thread_fence
// doesn't exist in these headers — use __threadfence() (agent-scope fence,
// the same call R9's correct-but-slow version used). Design: ONE
// __threadfence() before arrival (release: write back my stores), RELAXED
// polling (coherent L1-bypassing load, NO invalidate), ONE __threadfence()
// after exit (acquire: invalidate so we see others' stores).
// Valid: all 512 blocks co-resident by construction (LDS 73728 B ->
// exactly 2 blocks/CU; grid 512 = 256 CU x 2). Counters zeroed per launch
// by stream-ordered hipMemsetAsync (graph-capturable).
// ---------------------------------------------------------------------------
__device__ inline void gbar(unsigned* cnt, unsigned target) {
    __syncthreads();
    __threadfence();                       // release: make my writes visible
    if (threadIdx.x == 0) {
        __hip_atomic_fetch_add(cnt, 1u, __ATOMIC_RELAXED, __HIP_MEMORY_SCOPE_AGENT);
        while (__hip_atomic_load(cnt, __ATOMIC_RELAXED, __HIP_MEMORY_SCOPE_AGENT) < target)
            __builtin_amdgcn_s_sleep(8);
    }
    __syncthreads();
    __threadfence();                       // acquire: see others' writes
}

// ---------------------------------------------------------------------------
// FUSED single-launch MHA (normal launch + software barriers). Phase bodies
// are instruction-identical to measured-best standalone versions
// (prep/qkv: R3; flash: R7 80.1 µs pipeline; out: R3 (256,4) emulated as
// 2 two-wave sub-units with the same qt->XCD mapping). R9 proved the
// fusion logic correct (absmax 1.22e-4); this round only fixes the barrier.
//
// FRAGMENT-MAJOR LAYOUTS (unchanged):
//  A/B-frag canonical (16x16x32): elem j of lane (lrow=lane&15,quad=lane>>4)
//    A[m=lrow][k=kf*32+quad*8+j]  /  B[k=kf*32+quad*8+j][n=lrow]
//  Wf (Wq/Wk/Wv): [ct 128][kf 4][lane][8]; xf: [rt 256][kf 4][lane][8]
//  Qf/Kf: [bh][t 128][kf 4][lane][8]
//  Vf:  [bh][kb 32][nf 8][g 2][lane][8]  PERMUTED k
//  ctxf: [qt 256][kf 64][lane][8] PERMUTED k — written from flash O accs
//  Wof: [ct 8][kf 64][lane][8] PERMUTED k to MATCH ctxf
//  mbias pre-scaled by log2(e) (exp2 path).
// ---------------------------------------------------------------------------
__global__ __launch_bounds__(256, 2) void fused_mha(
        const float* __restrict__ x,   const int* __restrict__ mask,
        const float* __restrict__ Wq,  const float* __restrict__ bq,
        const float* __restrict__ Wk,  const float* __restrict__ bk,
        const float* __restrict__ Wv,  const float* __restrict__ bv,
        const float* __restrict__ Wo,  const float* __restrict__ bo,
        float* __restrict__ out,
        bf16* __restrict__ Wqf, bf16* __restrict__ Wkf, bf16* __restrict__ Wvf,
        bf16* __restrict__ Wof, bf16* __restrict__ xf,
        bf16* __restrict__ Qf,  bf16* __restrict__ Kf,  bf16* __restrict__ Vf,
        bf16* __restrict__ ctxf, float* __restrict__ mbias,
        unsigned* __restrict__ syncc)
{
    __shared__ __align__(16) char smem[73728];

    int bid = blockIdx.x, tid = threadIdx.x;
    int lane = tid & 63, wave = tid >> 6;
    int lrow = lane & 15, quad = lane >> 4;
    floatx4 zero4 = {0.f, 0.f, 0.f, 0.f};

    // ===================== phase P: prep (368 virtual blocks) =============
    {
        bf16* pw = (bf16*)smem;
        if (bid < 192) {
            // Wq/Wk/Wv [128][2048]: block = 64 k-rows (half) x 64 cols
            int m = bid / 64, rest = bid % 64;
            int cgp = rest >> 1, kh = rest & 1;
            const float* W = (m == 0) ? Wq : (m == 1) ? Wk : Wv;
            bf16* Wf       = (m == 0) ? Wqf : (m == 1) ? Wkf : Wvf;
            int slot = tid & 15, rowb = tid >> 4;
#pragma unroll
            for (int i = 0; i < 4; i++) {
                int rl_ = rowb + i * 16;
                float4 v = *(const float4*)(W + (size_t)(kh * 64 + rl_) * 2048 + cgp * 64 + slot * 4);
                bf16x4 o; o[0]=(bf16)v.x; o[1]=(bf16)v.y; o[2]=(bf16)v.z; o[3]=(bf16)v.w;
                *(bf16x4*)(&pw[rl_ * 68 + slot * 4]) = o;
            }
            __syncthreads();
            int ctl = wave;
#pragma unroll
            for (int kfl = 0; kfl < 2; kfl++) {
                bf16x8 w;
#pragma unroll
                for (int j = 0; j < 8; j++) w[j] = pw[(kfl * 32 + quad * 8 + j) * 68 + ctl * 16 + lrow];
                *(bf16x8*)(Wf + (size_t)((cgp * 4 + ctl) * 4 + kh * 2 + kfl) * 512 + lane * 8) = w;
            }
        } else if (bid < 224) {
            // Wo [2048][128]: 128 k-rows x 64-col half, PERMUTED pack
            int idx = bid - 192;
            int kb16 = idx >> 1, ch = idx & 1;
            int k0 = kb16 * 128;
            int slot = tid & 15, rowb = tid >> 4;
#pragma unroll
            for (int i = 0; i < 8; i++) {
                int r = rowb + i * 16;
                float4 v = *(const float4*)(Wo + (size_t)(k0 + r) * 128 + ch * 64 + slot * 4);
                bf16x4 o; o[0]=(bf16)v.x; o[1]=(bf16)v.y; o[2]=(bf16)v.z; o[3]=(bf16)v.w;
                *(bf16x4*)(&pw[r * 68 + slot * 4]) = o;
            }
            __syncthreads();
            int ctl = wave;
            int ct = ch * 4 + ctl;
#pragma unroll
            for (int kfl = 0; kfl < 4; kfl++) {
                bf16x8 w;
#pragma unroll
                for (int j = 0; j < 8; j++)
                    w[j] = pw[(kfl * 32 + ((j >> 2) << 4) + quad * 4 + (j & 3)) * 68 + ctl * 16 + lrow];
                *(bf16x8*)(Wof + (size_t)(ct * 64 + kb16 * 4 + kfl) * 512 + lane * 8) = w;
            }
        } else if (bid < 352) {
            // x [4096][128] fp32 -> xf frags, 32 rows per virtual block
            int idx = bid - 224, r0 = idx * 32;
            int slot = tid & 31, rowb = tid >> 5;
#pragma unroll
            for (int i = 0; i < 4; i++) {
                int r = rowb + i * 8;
                float4 v = *(const float4*)(x + (size_t)(r0 + r) * 128 + slot * 4);
                bf16x4 o; o[0]=(bf16)v.x; o[1]=(bf16)v.y; o[2]=(bf16)v.z; o[3]=(bf16)v.w;
                *(bf16x4*)(&pw[r * 136 + slot * 4]) = o;
            }
            __syncthreads();
            int rtl = wave >> 1;
            int kf2 = (wave & 1) * 2;
#pragma unroll
            for (int kfl = 0; kfl < 2; kfl++) {
                int kf = kf2 + kfl;
                bf16x8 w = *(const bf16x8*)(&pw[(rtl * 16 + lrow) * 136 + kf * 32 + quad * 8]);
                *(bf16x8*)(xf + (size_t)((idx * 2 + rtl) * 4 + kf) * 512 + lane * 8) = w;
            }
        } else if (bid < 368) {
            int e = (bid - 352) * 256 + tid;
            mbias[e] = mask[e] ? 0.0f : -43.2808512f;   // exp2 -> ~9e-14 ~ 0
        }
    }
    gbar(&syncc[0], 512);

    // ===================== phase A: qkv (4 chunks per block) ==============
    {
        bf16 (*tile)[72] = (bf16(*)[72])smem;
        for (int chunk = 0; chunk < 4; chunk++) {
            int vb = bid * 4 + chunk;          // x-fastest: vb&63 = row-blk
            int r0b = (vb & 63) * 64;
            int c0  = (vb >> 6) * 64;
            int cg4 = c0 >> 4;

            int rt = (r0b >> 4) + wave;
            bf16x8 a[4];
#pragma unroll
            for (int kf = 0; kf < 4; kf++)
                a[kf] = *(const bf16x8*)(xf + (size_t)(rt * 4 + kf) * 512 + lane * 8);

            int bb = r0b >> 11;
            int h  = c0 >> 7;
            int bhw = bb * 16 + h;
            int tile16 = (r0b & 2047) >> 4;
            int kbt = (r0b & 2047) >> 6;

#pragma unroll
            for (int z = 0; z < 3; z++) {
                const float* bias = (z == 0) ? bq : (z == 1) ? bk : bv;
                const bf16*  Wf   = (z == 0) ? Wqf : (z == 1) ? Wkf : Wvf;

                floatx4 acc[4] = {zero4, zero4, zero4, zero4};
#pragma unroll
                for (int kf = 0; kf < 4; kf++) {
#pragma unroll
                    for (int nf = 0; nf < 4; nf++) {
                        bf16x8 b = *(const bf16x8*)(Wf + (size_t)((cg4 + nf) * 4 + kf) * 512 + lane * 8);
                        acc[nf] = MFMA32K(a[kf], b, acc[nf]);
                    }
                }

#pragma unroll
                for (int nf = 0; nf < 4; nf++) {
                    int col = nf * 16 + lrow;
                    float bvv = bias[c0 + col];
#pragma unroll
                    for (int r = 0; r < 4; r++) {
                        int row = wave * 16 + quad * 4 + r;
                        bf16 val = (bf16)(acc[nf][r] + bvv);
                        if (z < 2) tile[row][col] = val;
                        else       tile[col][row] = val;
                    }
                }
                __syncthreads();

                if (z < 2) {
                    bf16* dst = (z == 0) ? Qf : Kf;
                    int s = wave;
                    int kfbase = (c0 & 127) >> 5;
                    size_t fbase = ((size_t)bhw * 128 + tile16 + s) * 4 + kfbase;
#pragma unroll
                    for (int kfl = 0; kfl < 2; kfl++) {
                        bf16x8 w = *(const bf16x8*)(&tile[s * 16 + lrow][kfl * 32 + quad * 8]);
                        *(bf16x8*)(dst + (fbase + kfl) * 512 + lane * 8) = w;
                    }
                } else {
                    int nfl = wave;
                    int nfbase = (c0 & 127) >> 4;
                    size_t fbase = (((size_t)bhw * 32 + kbt) * 8 + (nfbase + nfl)) * 2;
#pragma unroll
                    for (int g = 0; g < 2; g++) {
                        bf16x4 a0 = *(const bf16x4*)(&tile[nfl * 16 + lrow][g * 32 + quad * 4]);
                        bf16x4 a1 = *(const bf16x4*)(&tile[nfl * 16 + lrow][g * 32 + 16 + quad * 4]);
                        bf16x8 w;
                        w[0]=a0[0]; w[1]=a0[1]; w[2]=a0[2]; w[3]=a0[3];
                        w[4]=a1[0]; w[5]=a1[1]; w[6]=a1[2]; w[7]=a1[3];
                        *(bf16x8*)(Vf + (fbase + g) * 512 + lane * 8) = w;
                    }
                }
                if (z < 2) __syncthreads();
            }
            __syncthreads();   // protect tile before next chunk overwrites
        }
    }
    gbar(&syncc[1], 512);

    // ===================== phase F: flash (R7 pipelined body) =============
    {
        bf16* sm = (bf16*)smem;                 // 4 rotating K bufs x 16 KB
        float* mbL = (float*)(smem + 65536);    // mbias row (8 KB)

        int xcd = bid & 7, seq = bid >> 3;
        int bh  = xcd * 4 + (seq >> 4);
        int qblk = seq & 15;
        int b  = bh >> 4;
        int q0 = qblk * 128 + wave * 32;

        const float* mbp = mbias + b * N_;
        const bf16* kbase = Kf + (size_t)bh * 262144;
        const bf16* vbase = Vf + (size_t)bh * 262144 + lane * 8;

        bf16x8 qf[2][4];
#pragma unroll
        for (int u = 0; u < 2; u++)
#pragma unroll
            for (int kf = 0; kf < 4; kf++)
                qf[u][kf] = *(const bf16x8*)(Qf + (size_t)(((size_t)bh * 128 + (q0 >> 4) + u) * 4 + kf) * 512 + lane * 8);

        bf16x8 ones;
#pragma unroll
        for (int j = 0; j < 8; j++) ones[j] = (bf16)1.0f;

        floatx4 O[2][8];
#pragma unroll
        for (int u = 0; u < 2; u++)
#pragma unroll
            for (int nf = 0; nf < 8; nf++) O[u][nf] = zero4;
        floatx4 Oext[2] = {zero4, zero4};

        const float scale = 0.12751742f;        // (1/sqrt(128)) * log2(e)

        // prologue: K(0..2) -> buf0..2 + mbias; drain once
#pragma unroll
        for (int tt = 0; tt < 3; tt++) {
#pragma unroll
            for (int i = 0; i < 4; i++) {
                int seg = wave * 4 + i;
                load_lds16(kbase + (size_t)tt * 8192 + seg * 512 + lane * 8,
                           &sm[tt * 8192 + seg * 512]);
            }
        }
#pragma unroll
        for (int i = 0; i < 2; i++) {
            int seg = wave * 2 + i;
            load_lds16((const bf16*)(mbp + seg * 256) + lane * 8, (bf16*)(mbL + seg * 256));
        }
        __builtin_amdgcn_s_waitcnt(WAITCNT_VM(0));
        __builtin_amdgcn_s_barrier();

        // prologue compute: QK(0) -> pa/pb
        bf16x8 pa[2], pb[2];
#pragma unroll
        for (int s = 0; s < 4; s++) {
            floatx4 S0 = zero4, S1 = zero4;
            __builtin_amdgcn_s_setprio(1);
#pragma unroll
            for (int kf = 0; kf < 4; kf++) {
                bf16x8 kfr = *(const bf16x8*)(&sm[((s * 4 + kf) * 64 + lane) * 8]);
                S0 = MFMA32K(kfr, qf[0][kf], S0);
                S1 = MFMA32K(kfr, qf[1][kf], S1);
            }
            __builtin_amdgcn_s_setprio(0);
            float4 mb4 = *(const float4*)(mbL + s * 16 + quad * 4);
            const float* mbr = (const float*)&mb4;
            int o = (s & 1) * 4;
#pragma unroll
            for (int r = 0; r < 4; r++) {
                float p0 = __builtin_amdgcn_exp2f(fmaf(S0[r], scale, mbr[r]));
                float p1 = __builtin_amdgcn_exp2f(fmaf(S1[r], scale, mbr[r]));
                if (s < 2) { pa[0][o + r] = (bf16)p0; pa[1][o + r] = (bf16)p1; }
                else       { pb[0][o + r] = (bf16)p0; pb[1][o + r] = (bf16)p1; }
            }
        }

        for (int t = 0; t < 32; t++) {
            const bf16* vsrc = vbase + (size_t)t * 8192;
            bf16x8 vreg[16];
#pragma unroll
            for (int f = 0; f < 16; f++)
                vreg[f] = *(const bf16x8*)(vsrc + f * 512);

            if (t < 29) {
                int dst = ((t + 3) & 3) << 13;
                const bf16* ksrc = kbase + (size_t)(t + 3) * 8192;
#pragma unroll
                for (int i = 0; i < 4; i++) {
                    int seg = wave * 4 + i;
                    load_lds16(ksrc + seg * 512 + lane * 8, &sm[dst + seg * 512]);
                }
            }

            int nb = ((t + 1) & 3) << 13;
            int tn = t + 1;
            bf16x8 pan[2], pbn[2];
            floatx4 Sa0, Sa1, Sb0, Sb1;

            if (t < 31) {
                Sa0 = zero4; Sa1 = zero4; Sb0 = zero4; Sb1 = zero4;
                __builtin_amdgcn_s_setprio(1);
#pragma unroll
                for (int kf = 0; kf < 4; kf++) {
                    bf16x8 kfr = *(const bf16x8*)(&sm[nb + ((0 * 4 + kf) * 64 + lane) * 8]);
                    Sa0 = MFMA32K(kfr, qf[0][kf], Sa0);
                    Sa1 = MFMA32K(kfr, qf[1][kf], Sa1);
                }
#pragma unroll
                for (int kf = 0; kf < 4; kf++) {
                    bf16x8 kfr = *(const bf16x8*)(&sm[nb + ((1 * 4 + kf) * 64 + lane) * 8]);
                    Sb0 = MFMA32K(kfr, qf[0][kf], Sb0);
                    Sb1 = MFMA32K(kfr, qf[1][kf], Sb1);
                }
                __builtin_amdgcn_s_setprio(0);
                float4 mb4 = *(const float4*)(mbL + tn * 64 + 0 * 16 + quad * 4);
                const float* mbr = (const float*)&mb4;
#pragma unroll
                for (int r = 0; r < 4; r++) {
                    pan[0][r] = (bf16)__builtin_amdgcn_exp2f(fmaf(Sa0[r], scale, mbr[r]));
                    pan[1][r] = (bf16)__builtin_amdgcn_exp2f(fmaf(Sa1[r], scale, mbr[r]));
                }
            }

            __builtin_amdgcn_s_setprio(1);
            Oext[0] = MFMA32K(ones, pa[0], Oext[0]);
            Oext[1] = MFMA32K(ones, pa[1], Oext[1]);
#pragma unroll
            for (int nf = 0; nf < 8; nf++) {
                O[0][nf] = MFMA32K(vreg[nf * 2], pa[0], O[0][nf]);
                O[1][nf] = MFMA32K(vreg[nf * 2], pa[1], O[1][nf]);
            }
            __builtin_amdgcn_s_setprio(0);

            if (t < 31) {
                float4 mb4 = *(const float4*)(mbL + tn * 64 + 1 * 16 + quad * 4);
                const float* mbr = (const float*)&mb4;
#pragma unroll
                for (int r = 0; r < 4; r++) {
                    pan[0][4 + r] = (bf16)__builtin_amdgcn_exp2f(fmaf(Sb0[r], scale, mbr[r]));
                    pan[1][4 + r] = (bf16)__builtin_amdgcn_exp2f(fmaf(Sb1[r], scale, mbr[r]));
                }
                Sa0 = zero4; Sa1 = zero4; Sb0 = zero4; Sb1 = zero4;
                __builtin_amdgcn_s_setprio(1);
#pragma unroll
                for (int kf = 0; kf < 4; kf++) {
                    bf16x8 kfr = *(const bf16x8*)(&sm[nb + ((2 * 4 + kf) * 64 + lane) * 8]);
                    Sa0 = MFMA32K(kfr, qf[0][kf], Sa0);
                    Sa1 = MFMA32K(kfr, qf[1][kf], Sa1);
                }
#pragma unroll
                for (int kf = 0; kf < 4; kf++) {
                    bf16x8 kfr = *(const bf16x8*)(&sm[nb + ((3 * 4 + kf) * 64 + lane) * 8]);
                    Sb0 = MFMA32K(kfr, qf[0][kf], Sb0);
                    Sb1 = MFMA32K(kfr, qf[1][kf], Sb1);
                }
                __builtin_amdgcn_s_setprio(0);
                float4 mb4b = *(const float4*)(mbL + tn * 64 + 2 * 16 + quad * 4);
                const float* mbr2 = (const float*)&mb4b;
#pragma unroll
                for (int r = 0; r < 4; r++) {
                    pbn[0][r] = (bf16)__builtin_amdgcn_exp2f(fmaf(Sa0[r], scale, mbr2[r]));
                    pbn[1][r] = (bf16)__builtin_amdgcn_exp2f(fmaf(Sa1[r], scale, mbr2[r]));
                }
            }

            __builtin_amdgcn_s_setprio(1);
            Oext[0] = MFMA32K(ones, pb[0], Oext[0]);
            Oext[1] = MFMA32K(ones, pb[1], Oext[1]);
#pragma unroll
            for (int nf = 0; nf < 8; nf++) {
                O[0][nf] = MFMA32K(vreg[nf * 2 + 1], pb[0], O[0][nf]);
                O[1][nf] = MFMA32K(vreg[nf * 2 + 1], pb[1], O[1][nf]);
            }
            __builtin_amdgcn_s_setprio(0);

            if (t < 31) {
                float4 mb4 = *(const float4*)(mbL + tn * 64 + 3 * 16 + quad * 4);
                const float* mbr = (const float*)&mb4;
#pragma unroll
                for (int r = 0; r < 4; r++) {
                    pbn[0][4 + r] = (bf16)__builtin_amdgcn_exp2f(fmaf(Sb0[r], scale, mbr[r]));
                    pbn[1][4 + r] = (bf16)__builtin_amdgcn_exp2f(fmaf(Sb1[r], scale, mbr[r]));
                }
#pragma unroll
                for (int u = 0; u < 2; u++) { pa[u] = pan[u]; pb[u] = pbn[u]; }
            }

            __builtin_amdgcn_s_waitcnt(WAITCNT_VM(4));
            __builtin_amdgcn_s_barrier();
        }

        // epilogue: normalize + DIRECT permuted-concat A-frag stores
        const int* mp = mask + b * N_;
        int h4 = (bh & 15) * 4;
        size_t qtb = (size_t)b * 128 + (q0 >> 4);
#pragma unroll
        for (int u = 0; u < 2; u++) {
            float lsum = Oext[u][0];
            int q = q0 + u * 16 + lrow;
            float rl = (mp[q] && lsum > 0.f) ? (1.0f / lsum) : 0.f;
#pragma unroll
            for (int g = 0; g < 4; g++) {
                bf16x8 w;
#pragma unroll
                for (int j = 0; j < 4; j++) {
                    w[j]     = (bf16)(O[u][2 * g][j]     * rl);
                    w[j + 4] = (bf16)(O[u][2 * g + 1][j] * rl);
                }
                *(bf16x8*)(ctxf + ((qtb + u) * 64 + h4 + g) * 512 + lane * 8) = w;
            }
        }
    }
    gbar(&syncc[2], 512);

    // ===================== phase O: out_proj (2 sub-units) ================
    // Emulates R3's grid (256,4) x 128thr: sub-unit su handles virtual
    // block vb = su*512 + bid -> qt = vb&255, cty = vb>>8. A qt's four cty
    // land on bids {qt, qt+256} (same XCD mod 8) matching R3's L2 locality.
    {
        float* red = (float*)smem;             // [2 sub][512]
        int sub = wave >> 1, w2 = wave & 1;
        int vb = sub * 512 + bid;
        int qt = vb & 255, cty = vb >> 8;      // bid<256: cty 0/2; else 1/3
        int ct = cty * 2;
        int r0 = qt * 16, c0 = ct * 16;

        floatx4 acc[2] = {zero4, zero4};
        const bf16* ap = ctxf + ((size_t)qt * 64 + w2 * 32) * 512 + lane * 8;
        const bf16* b0 = Wof + ((size_t)ct * 64 + w2 * 32) * 512 + lane * 8;
        const bf16* b1 = b0 + (size_t)64 * 512;
#pragma unroll 4
        for (int kf = 0; kf < 32; kf++) {
            bf16x8 a  = *(const bf16x8*)(ap + (size_t)kf * 512);
            bf16x8 w0 = *(const bf16x8*)(b0 + (size_t)kf * 512);
            bf16x8 w1 = *(const bf16x8*)(b1 + (size_t)kf * 512);
            acc[0] = MFMA32K(a, w0, acc[0]);
            acc[1] = MFMA32K(a, w1, acc[1]);
        }
        if (w2 == 1) {
#pragma unroll
            for (int nf = 0; nf < 2; nf++)
#pragma unroll
                for (int r = 0; r < 4; r++)
                    red[sub * 512 + nf * 256 + r * 64 + lane] = acc[nf][r];
        }
        __syncthreads();
        if (w2 == 0) {
#pragma unroll
            for (int nf = 0; nf < 2; nf++) {
                int col = c0 + nf * 16 + lrow;
                float bv = bo[col];
#pragma unroll
                for (int r = 0; r < 4; r++) {
                    int m = r0 + quad * 4 + r;
                    out[(size_t)m * 128 + col] =
                        acc[nf][r] + red[sub * 512 + nf * 256 + r * 64 + lane] + bv;
                }
            }
        }
    }
}

// ---------------------------------------------------------------------------
extern "C" void kernel_launch(void* const* d_in, const int* in_sizes, int n_in,
                              void* d_out, int out_size, void* d_ws, size_t ws_size,
                              hipStream_t stream) {
    const float* x    = (const float*)d_in[0];
    const int*   mask = (const int*)d_in[1];
    const float* Wq   = (const float*)d_in[2];
    const float* bq   = (const float*)d_in[3];
    const float* Wk   = (const float*)d_in[4];
    const float* bk   = (const float*)d_in[5];
    const float* Wv   = (const float*)d_in[6];
    const float* bv   = (const float*)d_in[7];
    const float* Wo   = (const float*)d_in[8];
    const float* bo   = (const float*)d_in[9];
    float* out = (float*)d_out;

    char* ws = (char*)d_ws;
    size_t off = 0;
    bf16* Wqf = (bf16*)(ws + off); off += (size_t)262144 * 2;
    bf16* Wkf = (bf16*)(ws + off); off += (size_t)262144 * 2;
    bf16* Wvf = (bf16*)(ws + off); off += (size_t)262144 * 2;
    bf16* Wof = (bf16*)(ws + off); off += (size_t)262144 * 2;
    bf16* xf  = (bf16*)(ws + off); off += (size_t)524288 * 2;
    size_t qkv_elems = (size_t)BH_ * N_ * 128;           // 8.4M
    bf16* Qf  = (bf16*)(ws + off); off += qkv_elems * 2; // fragment-major
    bf16* Kf  = (bf16*)(ws + off); off += qkv_elems * 2;
    bf16* Vf  = (bf16*)(ws + off); off += qkv_elems * 2;
    bf16* ctxf = (bf16*)(ws + off); off += (size_t)M_ * ALL_ * 2;
    float* mbias = (float*)(ws + off); off += (size_t)B_ * N_ * 4;
    unsigned* syncc = (unsigned*)(ws + off); off += 256; // 3 barrier counters
    (void)ws_size; (void)in_sizes; (void)n_in; (void)out_size;

    (void)hipMemsetAsync(syncc, 0, 3 * sizeof(unsigned), stream);

    fused_mha<<<512, 256, 0, stream>>>(x, mask, Wq, bq, Wk, bk, Wv, bv, Wo, bo,
                                       out, Wqf, Wkf, Wvf, Wof, xf,
                                       Qf, Kf, Vf, ctxf, mbias, syncc);
}